// Round 5
// baseline (325.962 us; speedup 1.0000x reference)
//
#include <hip/hip_runtime.h>
#include <hip/hip_bf16.h>
#include <cstdint>
#include <cmath>

typedef __bf16 bf16_t;
typedef __attribute__((ext_vector_type(8))) bf16_t bf16x8;
typedef __attribute__((ext_vector_type(4))) float f32x4;

#define AS_GLOBAL(p) ((const __attribute__((address_space(1))) void*)(p))
#define AS_LDS(p)    ((__attribute__((address_space(3))) void*)(p))

// fp32 -> bf16 RTNE
__device__ __forceinline__ unsigned short f2bf(float f) {
  unsigned u = __builtin_bit_cast(unsigned, f);
  u += 0x7FFFu + ((u >> 16) & 1u);
  return (unsigned short)(u >> 16);
}

// ---------------- fused convert fp32 -> bf16 (x4 vectorized) ----------------
#define N4_X  2097152
#define N4_W  1048576
__global__ void cvt3_kernel(const float* __restrict__ x, const float* __restrict__ wq,
                            const float* __restrict__ wk, ushort4* __restrict__ xb4,
                            ushort4* __restrict__ wb4, float scale) {
  int i = blockIdx.x * blockDim.x + threadIdx.x;
  int stride = gridDim.x * blockDim.x;
  for (; i < N4_X + 2 * N4_W; i += stride) {
    const float4* src;
    ushort4* dst;
    float sc = 1.0f;
    if (i < N4_X) {
      src = reinterpret_cast<const float4*>(x) + i;
      dst = xb4 + i;
    } else if (i < N4_X + N4_W) {
      src = reinterpret_cast<const float4*>(wq) + (i - N4_X);
      dst = wb4 + (i - N4_X);
      sc = scale;
    } else {
      src = reinterpret_cast<const float4*>(wk) + (i - N4_X - N4_W);
      dst = wb4 + (i - N4_X);
    }
    float4 v = *src;
    ushort4 o;
    o.x = f2bf(v.x * sc);
    o.y = f2bf(v.y * sc);
    o.z = f2bf(v.z * sc);
    o.w = f2bf(v.w * sc);
    *dst = o;
  }
}

// ---------------- projection GEMM (unchanged, proven) ----------------
#define PM 4096
#define PN 4096
#define PK 2048

__global__ __launch_bounds__(256) void proj_gemm(const unsigned short* __restrict__ A,
                                                 const unsigned short* __restrict__ Bm,
                                                 unsigned short* __restrict__ C) {
  __shared__ unsigned short As[128 * 64];
  __shared__ unsigned short Bs[128 * 64];
  const int tid = threadIdx.x;
  const int wave = tid >> 6, lane = tid & 63;
  const int m0 = blockIdx.y * 128;
  const int n0 = blockIdx.x * 128;
  const int wr = wave >> 1, wc = wave & 1;

  f32x4 acc[4][4] = {};

  for (int kt = 0; kt < PK; kt += 64) {
    #pragma unroll
    for (int j = 0; j < 4; ++j) {
      int base = (wave * 4 + j) * 1024;
      int o = base + lane * 16;
      int row = o >> 7;
      int c = o & 127;
      int csrc = c ^ ((row & 7) << 4);
      const char* ga = (const char*)(A + (size_t)(m0 + row) * PK + kt) + csrc;
      __builtin_amdgcn_global_load_lds(AS_GLOBAL(ga), AS_LDS((char*)As + base), 16, 0, 0);
      const char* gb = (const char*)(Bm + (size_t)(n0 + row) * PK + kt) + csrc;
      __builtin_amdgcn_global_load_lds(AS_GLOBAL(gb), AS_LDS((char*)Bs + base), 16, 0, 0);
    }
    __syncthreads();

    #pragma unroll
    for (int ks = 0; ks < 2; ++ks) {
      bf16x8 av[4], bv[4];
      const int kbyte = ks * 64 + (lane >> 4) * 16;
      #pragma unroll
      for (int i = 0; i < 4; ++i) {
        int row = wr * 64 + i * 16 + (lane & 15);
        int off = row * 128 + (kbyte ^ ((row & 7) << 4));
        av[i] = *(const bf16x8*)((const char*)As + off);
      }
      #pragma unroll
      for (int j = 0; j < 4; ++j) {
        int row = wc * 64 + j * 16 + (lane & 15);
        int off = row * 128 + (kbyte ^ ((row & 7) << 4));
        bv[j] = *(const bf16x8*)((const char*)Bs + off);
      }
      #pragma unroll
      for (int i = 0; i < 4; ++i)
        #pragma unroll
        for (int j = 0; j < 4; ++j)
          acc[i][j] = __builtin_amdgcn_mfma_f32_16x16x32_bf16(av[i], bv[j], acc[i][j], 0, 0, 0);
    }
    __syncthreads();
  }

  #pragma unroll
  for (int i = 0; i < 4; ++i)
    #pragma unroll
    for (int j = 0; j < 4; ++j)
      #pragma unroll
      for (int r = 0; r < 4; ++r) {
        int row = m0 + wr * 64 + i * 16 + (lane >> 4) * 4 + r;
        int col = n0 + wc * 64 + j * 16 + (lane & 15);
        C[(size_t)row * PN + col] = f2bf(acc[i][j][r]);
      }
}

// ---------------- scores kernel v4: + chunked XCD swizzle, nontemporal stores ----------------
// 512 blocks 1-D; chunked bijective swizzle maps all 16 qtiles of one (b,h)
// onto the SAME XCD (4 bh-panels/XCD = 2MB K working set in 4MB L2).
// Output (537 MB, never re-read) uses nontemporal stores -> no L2 eviction
// pressure on the K panels.
__global__ __launch_bounds__(256) void scores_kernel(const unsigned short* __restrict__ qk,
                                                     float* __restrict__ out2) {
  __shared__ unsigned short Ks[2][128 * 128];
  const int tid = threadIdx.x;
  const int wave = tid >> 6, lane = tid & 63;
  const int bid = blockIdx.x;
  const int nid = (bid & 7) * 64 + (bid >> 3);   // chunked XCD swizzle (512 % 8 == 0: bijective)
  const int qtile = nid & 15;
  const int bh = nid >> 4;
  const int b = bh >> 4, h = bh & 15;
  const int wr = wave >> 1, wc = wave & 1;

  const unsigned short* qbase = qk + (size_t)(b * 2048 + qtile * 128) * 4096 + h * 128;
  const unsigned short* kbase = qk + (size_t)(b * 2048) * 4096 + 2048 + h * 128;

  // ---- load Q fragments straight to registers (A-operand layout) ----
  bf16x8 qv[4][4];
  #pragma unroll
  for (int i = 0; i < 4; ++i) {
    int row = wr * 64 + i * 16 + (lane & 15);
    const unsigned short* qr = qbase + (size_t)row * 4096 + (lane >> 4) * 8;
    #pragma unroll
    for (int ks = 0; ks < 4; ++ks)
      qv[i][ks] = *(const bf16x8*)(qr + ks * 32);
  }

  auto stageK = [&](int bi, int kt) {
    const unsigned short* kb = kbase + (size_t)kt * 128 * 4096;
    #pragma unroll
    for (int j = 0; j < 8; ++j) {
      int base = (wave * 8 + j) * 1024;
      int o = base + lane * 16;
      int row = o >> 8;
      int c = o & 255;
      int csrc = c ^ ((row & 7) << 4);
      const char* gk = (const char*)(kb + (size_t)row * 4096) + csrc;
      __builtin_amdgcn_global_load_lds(AS_GLOBAL(gk), AS_LDS((char*)Ks[bi] + base), 16, 0, 0);
    }
  };

  float* obase = out2 + ((size_t)(b * 2048 + qtile * 128) * 16 + h) * 2048;
  const size_t qstride = (size_t)16 * 2048;

  stageK(0, 0);
  __syncthreads();

  int cur = 0;
  for (int kt = 0; kt < 16; ++kt) {
    if (kt + 1 < 16) stageK(cur ^ 1, kt + 1);

    f32x4 acc[4][4] = {};
    #pragma unroll
    for (int ks = 0; ks < 4; ++ks) {
      bf16x8 bv[4];
      const int kbyte = ks * 64 + (lane >> 4) * 16;
      #pragma unroll
      for (int j = 0; j < 4; ++j) {
        int row = wc * 64 + j * 16 + (lane & 15);
        int off = row * 256 + (kbyte ^ ((row & 7) << 4));
        bv[j] = *(const bf16x8*)((const char*)Ks[cur] + off);
      }
      #pragma unroll
      for (int i = 0; i < 4; ++i)
        #pragma unroll
        for (int j = 0; j < 4; ++j)
          acc[i][j] = __builtin_amdgcn_mfma_f32_16x16x32_bf16(qv[i][ks], bv[j], acc[i][j], 0, 0, 0);
    }

    __syncthreads();

    // nontemporal stores: streaming output, bypass L2
    #pragma unroll
    for (int i = 0; i < 4; ++i)
      #pragma unroll
      for (int j = 0; j < 4; ++j)
        #pragma unroll
        for (int r = 0; r < 4; ++r) {
          int qrow = wr * 64 + i * 16 + (lane >> 4) * 4 + r;
          int col = kt * 128 + wc * 64 + j * 16 + (lane & 15);
          __builtin_nontemporal_store(acc[i][j][r], &obase[(size_t)qrow * qstride + col]);
        }

    cur ^= 1;
  }
}

extern "C" void kernel_launch(void* const* d_in, const int* in_sizes, int n_in,
                              void* d_out, int out_size, void* d_ws, size_t ws_size,
                              hipStream_t stream) {
  const float* x  = (const float*)d_in[0];
  const float* Wq = (const float*)d_in[1];
  const float* Wk = (const float*)d_in[2];
  // d_in[3] = Wv: computed then discarded by the reference -> skipped entirely.

  float* out = (float*)d_out;                             // fp32 output
  unsigned short* xb = (unsigned short*)d_ws;             // x as bf16      [4096][2048]
  unsigned short* wb = xb + (size_t)4096 * 2048;          // [Wq*scale; Wk] [4096][2048]
  unsigned short* qkbuf = wb + (size_t)4096 * 2048;       // Q||K           [4096][4096]

  const float scale = 1.0f / sqrtf(128.0f);

  // Output 0: attn_output = zeros, fp32, 2*2048*2048 elements (33.5 MB)
  hipMemsetAsync(d_out, 0, (size_t)2 * 2048 * 2048 * sizeof(float), stream);

  cvt3_kernel<<<2048, 256, 0, stream>>>(x, Wq, Wk, (ushort4*)xb, (ushort4*)wb, scale);

  proj_gemm<<<dim3(PN / 128, PM / 128), 256, 0, stream>>>(xb, wb, qkbuf);

  // Output 1: attn_weights fp32 at element offset 2*2048*2048
  scores_kernel<<<512, 256, 0, stream>>>(qkbuf, out + (size_t)2 * 2048 * 2048);
}

// Round 6
// 263.891 us; speedup vs baseline: 1.2352x; 1.2352x over previous
//
#include <hip/hip_runtime.h>
#include <hip/hip_bf16.h>
#include <cstdint>
#include <cmath>

typedef __bf16 bf16_t;
typedef __attribute__((ext_vector_type(8))) bf16_t bf16x8;
typedef __attribute__((ext_vector_type(4))) float f32x4;

#define AS_GLOBAL(p) ((const __attribute__((address_space(1))) void*)(p))
#define AS_LDS(p)    ((__attribute__((address_space(3))) void*)(p))

// fp32 -> bf16 RTNE
__device__ __forceinline__ unsigned short f2bf(float f) {
  unsigned u = __builtin_bit_cast(unsigned, f);
  u += 0x7FFFu + ((u >> 16) & 1u);
  return (unsigned short)(u >> 16);
}

// ---------------- fused convert fp32 -> bf16 (x4 vectorized) ----------------
#define N4_X  2097152
#define N4_W  1048576
__global__ void cvt3_kernel(const float* __restrict__ x, const float* __restrict__ wq,
                            const float* __restrict__ wk, ushort4* __restrict__ xb4,
                            ushort4* __restrict__ wb4, float scale) {
  int i = blockIdx.x * blockDim.x + threadIdx.x;
  int stride = gridDim.x * blockDim.x;
  for (; i < N4_X + 2 * N4_W; i += stride) {
    const float4* src;
    ushort4* dst;
    float sc = 1.0f;
    if (i < N4_X) {
      src = reinterpret_cast<const float4*>(x) + i;
      dst = xb4 + i;
    } else if (i < N4_X + N4_W) {
      src = reinterpret_cast<const float4*>(wq) + (i - N4_X);
      dst = wb4 + (i - N4_X);
      sc = scale;
    } else {
      src = reinterpret_cast<const float4*>(wk) + (i - N4_X - N4_W);
      dst = wb4 + (i - N4_X);
    }
    float4 v = *src;
    ushort4 o;
    o.x = f2bf(v.x * sc);
    o.y = f2bf(v.y * sc);
    o.z = f2bf(v.z * sc);
    o.w = f2bf(v.w * sc);
    *dst = o;
  }
}

// ---------------- projection GEMM: operand-swapped -> ushort4 C stores ----------------
// C[4096][4096] = A[4096][2048] @ B[4096][2048]^T (bf16, fp32 accum).
// mfma(W_frag, x_frag, acc): D row axis = n (contiguous in C) -> the 4 accum
// regs pack into one ushort4 (8B) store instead of 64 scalar 2B stores.
#define PM 4096
#define PN 4096
#define PK 2048

__global__ __launch_bounds__(256) void proj_gemm(const unsigned short* __restrict__ A,
                                                 const unsigned short* __restrict__ Bm,
                                                 unsigned short* __restrict__ C) {
  __shared__ unsigned short As[128 * 64];
  __shared__ unsigned short Bs[128 * 64];
  const int tid = threadIdx.x;
  const int wave = tid >> 6, lane = tid & 63;
  const int m0 = blockIdx.y * 128;
  const int n0 = blockIdx.x * 128;
  const int wr = wave >> 1, wc = wave & 1;

  f32x4 acc[4][4] = {};   // [i: m-frag][j: n-frag]

  for (int kt = 0; kt < PK; kt += 64) {
    #pragma unroll
    for (int j = 0; j < 4; ++j) {
      int base = (wave * 4 + j) * 1024;
      int o = base + lane * 16;
      int row = o >> 7;
      int c = o & 127;
      int csrc = c ^ ((row & 7) << 4);
      const char* ga = (const char*)(A + (size_t)(m0 + row) * PK + kt) + csrc;
      __builtin_amdgcn_global_load_lds(AS_GLOBAL(ga), AS_LDS((char*)As + base), 16, 0, 0);
      const char* gb = (const char*)(Bm + (size_t)(n0 + row) * PK + kt) + csrc;
      __builtin_amdgcn_global_load_lds(AS_GLOBAL(gb), AS_LDS((char*)Bs + base), 16, 0, 0);
    }
    __syncthreads();

    #pragma unroll
    for (int ks = 0; ks < 2; ++ks) {
      bf16x8 av[4], bv[4];
      const int kbyte = ks * 64 + (lane >> 4) * 16;
      #pragma unroll
      for (int i = 0; i < 4; ++i) {
        int row = wr * 64 + i * 16 + (lane & 15);
        int off = row * 128 + (kbyte ^ ((row & 7) << 4));
        av[i] = *(const bf16x8*)((const char*)As + off);
      }
      #pragma unroll
      for (int j = 0; j < 4; ++j) {
        int row = wc * 64 + j * 16 + (lane & 15);
        int off = row * 128 + (kbyte ^ ((row & 7) << 4));
        bv[j] = *(const bf16x8*)((const char*)Bs + off);
      }
      // swapped: A-operand = W-frag (n-dim = M-of-mfma), B-operand = x-frag
      #pragma unroll
      for (int i = 0; i < 4; ++i)
        #pragma unroll
        for (int j = 0; j < 4; ++j)
          acc[i][j] = __builtin_amdgcn_mfma_f32_16x16x32_bf16(bv[j], av[i], acc[i][j], 0, 0, 0);
    }
    __syncthreads();
  }

  // D layout: row = n-frag-local = (lane>>4)*4 + r, col = m-frag-local = lane&15
  #pragma unroll
  for (int i = 0; i < 4; ++i) {
    int row = m0 + wr * 64 + i * 16 + (lane & 15);
    #pragma unroll
    for (int j = 0; j < 4; ++j) {
      int col = n0 + wc * 64 + j * 16 + (lane >> 4) * 4;
      ushort4 o;
      o.x = f2bf(acc[i][j][0]);
      o.y = f2bf(acc[i][j][1]);
      o.z = f2bf(acc[i][j][2]);
      o.w = f2bf(acc[i][j][3]);
      *(ushort4*)(&C[(size_t)row * PN + col]) = o;
    }
  }
}

// ---------------- scores kernel v5: operand-swapped -> float4 output stores ----------------
// One block per (qtile, b, h): dim3(16, 32) = 512 blocks = 2/CU.
// Q in registers; K streamed through 2x32KB LDS, 1-ahead prefetch.
// mfma(K_frag, Q_frag, acc): D row axis = k (contiguous in out) -> each
// acc[i][j] stores as ONE float4 (16 stores/lane/iter instead of 64).
__global__ __launch_bounds__(256) void scores_kernel(const unsigned short* __restrict__ qk,
                                                     float* __restrict__ out2) {
  __shared__ unsigned short Ks[2][128 * 128];
  const int tid = threadIdx.x;
  const int wave = tid >> 6, lane = tid & 63;
  const int qtile = blockIdx.x;
  const int bh = blockIdx.y;
  const int b = bh >> 4, h = bh & 15;
  const int wr = wave >> 1, wc = wave & 1;

  const unsigned short* qbase = qk + (size_t)(b * 2048 + qtile * 128) * 4096 + h * 128;
  const unsigned short* kbase = qk + (size_t)(b * 2048) * 4096 + 2048 + h * 128;

  // ---- Q fragments to registers (per-lane layout identical for A- and B-operand use) ----
  bf16x8 qv[4][4];
  #pragma unroll
  for (int i = 0; i < 4; ++i) {
    int row = wr * 64 + i * 16 + (lane & 15);
    const unsigned short* qr = qbase + (size_t)row * 4096 + (lane >> 4) * 8;
    #pragma unroll
    for (int ks = 0; ks < 4; ++ks)
      qv[i][ks] = *(const bf16x8*)(qr + ks * 32);
  }

  auto stageK = [&](int bi, int kt) {
    const unsigned short* kb = kbase + (size_t)kt * 128 * 4096;
    #pragma unroll
    for (int j = 0; j < 8; ++j) {
      int base = (wave * 8 + j) * 1024;
      int o = base + lane * 16;
      int row = o >> 8;
      int c = o & 255;
      int csrc = c ^ ((row & 7) << 4);
      const char* gk = (const char*)(kb + (size_t)row * 4096) + csrc;
      __builtin_amdgcn_global_load_lds(AS_GLOBAL(gk), AS_LDS((char*)Ks[bi] + base), 16, 0, 0);
    }
  };

  float* obase = out2 + ((size_t)(b * 2048 + qtile * 128) * 16 + h) * 2048;
  const size_t qstride = (size_t)16 * 2048;

  stageK(0, 0);
  __syncthreads();

  int cur = 0;
  for (int kt = 0; kt < 16; ++kt) {
    if (kt + 1 < 16) stageK(cur ^ 1, kt + 1);

    f32x4 acc[4][4] = {};   // [i: q-frag][j: k-frag]
    #pragma unroll
    for (int ks = 0; ks < 4; ++ks) {
      bf16x8 bv[4];
      const int kbyte = ks * 64 + (lane >> 4) * 16;
      #pragma unroll
      for (int j = 0; j < 4; ++j) {
        int row = wc * 64 + j * 16 + (lane & 15);
        int off = row * 256 + (kbyte ^ ((row & 7) << 4));
        bv[j] = *(const bf16x8*)((const char*)Ks[cur] + off);
      }
      // swapped: A-operand = K-frag, B-operand = Q-frag
      #pragma unroll
      for (int i = 0; i < 4; ++i)
        #pragma unroll
        for (int j = 0; j < 4; ++j)
          acc[i][j] = __builtin_amdgcn_mfma_f32_16x16x32_bf16(bv[j], qv[i][ks], acc[i][j], 0, 0, 0);
    }

    __syncthreads();   // this iter's stage loads done; prev stores long in flight

    // D layout: row = k-local = (lane>>4)*4 + r, col = q-local = lane&15
    // -> acc[i][j] is 4 consecutive k elements: one float4 store.
    #pragma unroll
    for (int i = 0; i < 4; ++i) {
      int qrow = wr * 64 + i * 16 + (lane & 15);
      float* orow = obase + (size_t)qrow * qstride + kt * 128;
      #pragma unroll
      for (int j = 0; j < 4; ++j) {
        int col = wc * 64 + j * 16 + (lane >> 4) * 4;
        *(float4*)(&orow[col]) = __builtin_bit_cast(float4, acc[i][j]);
      }
    }

    cur ^= 1;
  }
}

extern "C" void kernel_launch(void* const* d_in, const int* in_sizes, int n_in,
                              void* d_out, int out_size, void* d_ws, size_t ws_size,
                              hipStream_t stream) {
  const float* x  = (const float*)d_in[0];
  const float* Wq = (const float*)d_in[1];
  const float* Wk = (const float*)d_in[2];
  // d_in[3] = Wv: computed then discarded by the reference -> skipped entirely.

  float* out = (float*)d_out;                             // fp32 output
  unsigned short* xb = (unsigned short*)d_ws;             // x as bf16      [4096][2048]
  unsigned short* wb = xb + (size_t)4096 * 2048;          // [Wq*scale; Wk] [4096][2048]
  unsigned short* qkbuf = wb + (size_t)4096 * 2048;       // Q||K           [4096][4096]

  const float scale = 1.0f / sqrtf(128.0f);

  // Output 0: attn_output = zeros, fp32, 2*2048*2048 elements (33.5 MB)
  hipMemsetAsync(d_out, 0, (size_t)2 * 2048 * 2048 * sizeof(float), stream);

  cvt3_kernel<<<2048, 256, 0, stream>>>(x, Wq, Wk, (ushort4*)xb, (ushort4*)wb, scale);

  proj_gemm<<<dim3(PN / 128, PM / 128), 256, 0, stream>>>(xb, wb, qkbuf);

  // Output 1: attn_weights fp32 at element offset 2*2048*2048
  scores_kernel<<<dim3(16, 32), 256, 0, stream>>>(qkbuf, out + (size_t)2 * 2048 * 2048);
}

// Round 7
// 231.960 us; speedup vs baseline: 1.4053x; 1.1377x over previous
//
#include <hip/hip_runtime.h>
#include <hip/hip_bf16.h>
#include <cstdint>
#include <cmath>

typedef __bf16 bf16_t;
typedef __attribute__((ext_vector_type(8))) bf16_t bf16x8;
typedef __attribute__((ext_vector_type(4))) float f32x4;

#define AS_GLOBAL(p) ((const __attribute__((address_space(1))) void*)(p))
#define AS_LDS(p)    ((__attribute__((address_space(3))) void*)(p))

// fp32 -> bf16 RTNE
__device__ __forceinline__ unsigned short f2bf(float f) {
  unsigned u = __builtin_bit_cast(unsigned, f);
  u += 0x7FFFu + ((u >> 16) & 1u);
  return (unsigned short)(u >> 16);
}

// ---------------- fused convert fp32 -> bf16 (x4 vectorized) ----------------
#define N4_X  2097152
#define N4_W  1048576
__global__ void cvt3_kernel(const float* __restrict__ x, const float* __restrict__ wq,
                            const float* __restrict__ wk, ushort4* __restrict__ xb4,
                            ushort4* __restrict__ wb4, float scale) {
  int i = blockIdx.x * blockDim.x + threadIdx.x;
  int stride = gridDim.x * blockDim.x;
  for (; i < N4_X + 2 * N4_W; i += stride) {
    const float4* src;
    ushort4* dst;
    float sc = 1.0f;
    if (i < N4_X) {
      src = reinterpret_cast<const float4*>(x) + i;
      dst = xb4 + i;
    } else if (i < N4_X + N4_W) {
      src = reinterpret_cast<const float4*>(wq) + (i - N4_X);
      dst = wb4 + (i - N4_X);
      sc = scale;
    } else {
      src = reinterpret_cast<const float4*>(wk) + (i - N4_X - N4_W);
      dst = wb4 + (i - N4_X);
    }
    float4 v = *src;
    ushort4 o;
    o.x = f2bf(v.x * sc);
    o.y = f2bf(v.y * sc);
    o.z = f2bf(v.z * sc);
    o.w = f2bf(v.w * sc);
    *dst = o;
  }
}

// ================= projection GEMM: 256x256 tile, 8-phase schedule =================
// C[4096][4096] = A[4096][2048] @ B[4096][2048]^T (bf16, fp32 accum).
// 512 threads (8 waves, 2M x 4N), BK=64, 2-deep LDS dbuf (128 KB), counted vmcnt,
// two raw s_barriers per phase, setprio around MFMA cluster.
// Half-tile order per K-tile: A0,B0,A1,B1; stage runs 6 half-tiles ahead;
// quadrant phases: Q0=(A0,B0) Q1=(A0,B1) Q2=(A1,B0) Q3=(A1,B1).
// Ledger (loads, 2 per half-tile per thread): steady vmcnt {Q0:6,Q1:10,Q2:10,Q3:8}.
#define PM 4096
#define PN 4096
#define PK 2048
#define PNT 32   // K tiles

template<int VM> __device__ __forceinline__ void waitcnt_vm() {
  if constexpr (VM == 0)  asm volatile("s_waitcnt vmcnt(0)" ::: "memory");
  else if constexpr (VM == 2)  asm volatile("s_waitcnt vmcnt(2)" ::: "memory");
  else if constexpr (VM == 4)  asm volatile("s_waitcnt vmcnt(4)" ::: "memory");
  else if constexpr (VM == 6)  asm volatile("s_waitcnt vmcnt(6)" ::: "memory");
  else if constexpr (VM == 8)  asm volatile("s_waitcnt vmcnt(8)" ::: "memory");
  else if constexpr (VM == 10) asm volatile("s_waitcnt vmcnt(10)" ::: "memory");
  // VM < 0: no wait
}

// stage one 128x64 half-tile (16 KB): 2 x global_load_lds(16B) per thread
__device__ __forceinline__ void stage_half(const unsigned short* A, const unsigned short* B,
                                           int m0, int n0, int H, int wave, int lane,
                                           char* lds) {
  int tile = H >> 2;
  int mat  = H & 1;          // 0=A, 1=B
  int half = (H >> 1) & 1;
  int buf  = tile & 1;
  const unsigned short* src = mat ? B : A;
  int base0 = mat ? n0 : m0;
  char* hbase = lds + (((buf * 2 + mat) * 2 + half) * 16384);
  #pragma unroll
  for (int l = 0; l < 2; ++l) {
    int o = l * 8192 + wave * 1024 + lane * 16;
    int row = o >> 7;                  // 128B rows (BK=64 bf16)
    int c = o & 127;
    int csrc = c ^ ((row & 7) << 4);   // pre-swizzled global source
    const char* g = (const char*)(src + (size_t)(base0 + half * 128 + row) * PK)
                    + tile * 128 + csrc;
    __builtin_amdgcn_global_load_lds(AS_GLOBAL(g), AS_LDS(hbase + l * 8192 + wave * 1024),
                                     16, 0, 0);
  }
}

template<int Q, int VM>
__device__ __forceinline__ void phase(const unsigned short* A, const unsigned short* B,
                                      int m0, int n0, int T, int wave, int lane,
                                      int wm, int wn, char* lds, f32x4 (&acc)[8][4]) {
  constexpr int gm = Q >> 1, gn = Q & 1;
  const int buf = T & 1;
  const char* Ab = lds + (((buf * 2 + 0) * 2 + gm) * 16384);
  const char* Bb = lds + (((buf * 2 + 1) * 2 + gn) * 16384);

  // ds-load this quadrant's fragments (8 + 4 = 12 x ds_read_b128)
  bf16x8 av[4][2], bv[2][2];
  #pragma unroll
  for (int j = 0; j < 4; ++j) {
    int row = j * 32 + wm * 16 + (lane & 15);
    #pragma unroll
    for (int ks = 0; ks < 2; ++ks) {
      int kb = ks * 64 + (lane >> 4) * 16;
      av[j][ks] = *(const bf16x8*)(Ab + row * 128 + (kb ^ ((row & 7) << 4)));
    }
  }
  #pragma unroll
  for (int i = 0; i < 2; ++i) {
    int row = i * 64 + wn * 16 + (lane & 15);
    #pragma unroll
    for (int ks = 0; ks < 2; ++ks) {
      int kb = ks * 64 + (lane >> 4) * 16;
      bv[i][ks] = *(const bf16x8*)(Bb + row * 128 + (kb ^ ((row & 7) << 4)));
    }
  }

  // stage one half-tile, 6 ahead
  int H = 4 * T + Q + 6;
  if (H < 4 * PNT) stage_half(A, B, m0, n0, H, wave, lane, lds);

  waitcnt_vm<VM>();
  asm volatile("s_barrier" ::: "memory");
  asm volatile("s_waitcnt lgkmcnt(0)" ::: "memory");
  __builtin_amdgcn_sched_barrier(0);

  __builtin_amdgcn_s_setprio(1);
  #pragma unroll
  for (int j = 0; j < 4; ++j)
    #pragma unroll
    for (int i = 0; i < 2; ++i)
      #pragma unroll
      for (int ks = 0; ks < 2; ++ks)
        acc[gm * 4 + j][gn * 2 + i] =
          __builtin_amdgcn_mfma_f32_16x16x32_bf16(av[j][ks], bv[i][ks],
                                                  acc[gm * 4 + j][gn * 2 + i], 0, 0, 0);
  __builtin_amdgcn_s_setprio(0);
  asm volatile("s_barrier" ::: "memory");
}

__global__ __launch_bounds__(512, 2) void proj_gemm(const unsigned short* __restrict__ A,
                                                    const unsigned short* __restrict__ Bm,
                                                    unsigned short* __restrict__ C) {
  __shared__ __align__(16) char lds[131072];   // 2 buf x (A,B) x 2 half x 16KB
  const int tid = threadIdx.x;
  const int wave = tid >> 6, lane = tid & 63;
  const int wm = wave >> 2, wn = wave & 3;     // 2 x 4 waves
  const int m0 = blockIdx.y * 256;
  const int n0 = blockIdx.x * 256;

  f32x4 acc[8][4] = {};

  // prologue: stage halves 0..5 (12 loads); vmcnt(8) => halves 0,1 landed
  #pragma unroll
  for (int h = 0; h < 6; ++h) stage_half(A, Bm, m0, n0, h, wave, lane, lds);
  waitcnt_vm<8>();
  asm volatile("s_barrier" ::: "memory");

  for (int T = 0; T < PNT - 2; ++T) {
    phase<0, 6>(A, Bm, m0, n0, T, wave, lane, wm, wn, lds, acc);
    phase<1, 10>(A, Bm, m0, n0, T, wave, lane, wm, wn, lds, acc);
    phase<2, 10>(A, Bm, m0, n0, T, wave, lane, wm, wn, lds, acc);
    phase<3, 8>(A, Bm, m0, n0, T, wave, lane, wm, wn, lds, acc);
  }
  // T = 30: stages end mid-tile -> stricter counts
  phase<0, 6>(A, Bm, m0, n0, PNT - 2, wave, lane, wm, wn, lds, acc);
  phase<1, 10>(A, Bm, m0, n0, PNT - 2, wave, lane, wm, wn, lds, acc);
  phase<2, 8>(A, Bm, m0, n0, PNT - 2, wave, lane, wm, wn, lds, acc);
  phase<3, 4>(A, Bm, m0, n0, PNT - 2, wave, lane, wm, wn, lds, acc);
  // T = 31: drain fully at Q0, then no waits
  phase<0, 0>(A, Bm, m0, n0, PNT - 1, wave, lane, wm, wn, lds, acc);
  phase<1, -1>(A, Bm, m0, n0, PNT - 1, wave, lane, wm, wn, lds, acc);
  phase<2, -1>(A, Bm, m0, n0, PNT - 1, wave, lane, wm, wn, lds, acc);
  phase<3, -1>(A, Bm, m0, n0, PNT - 1, wave, lane, wm, wn, lds, acc);

  // epilogue: C/D layout row=(lane>>4)*4+r, col=lane&15 (proven mapping)
  #pragma unroll
  for (int f = 0; f < 8; ++f) {
    int rbase = m0 + (f >> 2) * 128 + (f & 3) * 32 + wm * 16 + (lane >> 4) * 4;
    #pragma unroll
    for (int nf = 0; nf < 4; ++nf) {
      int col = n0 + (nf >> 1) * 128 + (nf & 1) * 64 + wn * 16 + (lane & 15);
      #pragma unroll
      for (int r = 0; r < 4; ++r)
        C[(size_t)(rbase + r) * PN + col] = f2bf(acc[f][nf][r]);
    }
  }
}

// ---------------- scores kernel (R4-proven): persistent-Q, streaming-K ----------------
__global__ __launch_bounds__(256) void scores_kernel(const unsigned short* __restrict__ qk,
                                                     float* __restrict__ out2) {
  __shared__ unsigned short Ks[2][128 * 128];
  const int tid = threadIdx.x;
  const int wave = tid >> 6, lane = tid & 63;
  const int qtile = blockIdx.x;
  const int bh = blockIdx.y;
  const int b = bh >> 4, h = bh & 15;
  const int wr = wave >> 1, wc = wave & 1;

  const unsigned short* qbase = qk + (size_t)(b * 2048 + qtile * 128) * 4096 + h * 128;
  const unsigned short* kbase = qk + (size_t)(b * 2048) * 4096 + 2048 + h * 128;

  bf16x8 qv[4][4];
  #pragma unroll
  for (int i = 0; i < 4; ++i) {
    int row = wr * 64 + i * 16 + (lane & 15);
    const unsigned short* qr = qbase + (size_t)row * 4096 + (lane >> 4) * 8;
    #pragma unroll
    for (int ks = 0; ks < 4; ++ks)
      qv[i][ks] = *(const bf16x8*)(qr + ks * 32);
  }

  auto stageK = [&](int bi, int kt) {
    const unsigned short* kb = kbase + (size_t)kt * 128 * 4096;
    #pragma unroll
    for (int j = 0; j < 8; ++j) {
      int base = (wave * 8 + j) * 1024;
      int o = base + lane * 16;
      int row = o >> 8;
      int c = o & 255;
      int csrc = c ^ ((row & 7) << 4);
      const char* gk = (const char*)(kb + (size_t)row * 4096) + csrc;
      __builtin_amdgcn_global_load_lds(AS_GLOBAL(gk), AS_LDS((char*)Ks[bi] + base), 16, 0, 0);
    }
  };

  float* obase = out2 + ((size_t)(b * 2048 + qtile * 128) * 16 + h) * 2048;
  const size_t qstride = (size_t)16 * 2048;

  stageK(0, 0);
  __syncthreads();

  int cur = 0;
  for (int kt = 0; kt < 16; ++kt) {
    if (kt + 1 < 16) stageK(cur ^ 1, kt + 1);

    f32x4 acc[4][4] = {};
    #pragma unroll
    for (int ks = 0; ks < 4; ++ks) {
      bf16x8 bv[4];
      const int kbyte = ks * 64 + (lane >> 4) * 16;
      #pragma unroll
      for (int j = 0; j < 4; ++j) {
        int row = wc * 64 + j * 16 + (lane & 15);
        int off = row * 256 + (kbyte ^ ((row & 7) << 4));
        bv[j] = *(const bf16x8*)((const char*)Ks[cur] + off);
      }
      #pragma unroll
      for (int i = 0; i < 4; ++i)
        #pragma unroll
        for (int j = 0; j < 4; ++j)
          acc[i][j] = __builtin_amdgcn_mfma_f32_16x16x32_bf16(qv[i][ks], bv[j], acc[i][j], 0, 0, 0);
    }

    __syncthreads();

    #pragma unroll
    for (int i = 0; i < 4; ++i)
      #pragma unroll
      for (int j = 0; j < 4; ++j)
        #pragma unroll
        for (int r = 0; r < 4; ++r) {
          int qrow = wr * 64 + i * 16 + (lane >> 4) * 4 + r;
          int col = kt * 128 + wc * 64 + j * 16 + (lane & 15);
          obase[(size_t)qrow * qstride + col] = acc[i][j][r];
        }

    cur ^= 1;
  }
}

extern "C" void kernel_launch(void* const* d_in, const int* in_sizes, int n_in,
                              void* d_out, int out_size, void* d_ws, size_t ws_size,
                              hipStream_t stream) {
  const float* x  = (const float*)d_in[0];
  const float* Wq = (const float*)d_in[1];
  const float* Wk = (const float*)d_in[2];
  // d_in[3] = Wv: computed then discarded by the reference -> skipped entirely.

  float* out = (float*)d_out;                             // fp32 output
  unsigned short* xb = (unsigned short*)d_ws;             // x as bf16      [4096][2048]
  unsigned short* wb = xb + (size_t)4096 * 2048;          // [Wq*scale; Wk] [4096][2048]
  unsigned short* qkbuf = wb + (size_t)4096 * 2048;       // Q||K           [4096][4096]

  const float scale = 1.0f / sqrtf(128.0f);

  // Output 0: attn_output = zeros, fp32, 2*2048*2048 elements (33.5 MB)
  hipMemsetAsync(d_out, 0, (size_t)2 * 2048 * 2048 * sizeof(float), stream);

  cvt3_kernel<<<2048, 256, 0, stream>>>(x, Wq, Wk, (ushort4*)xb, (ushort4*)wb, scale);

  proj_gemm<<<dim3(PN / 256, PM / 256), 512, 0, stream>>>(xb, wb, qkbuf);

  // Output 1: attn_weights fp32 at element offset 2*2048*2048
  scores_kernel<<<dim3(16, 32), 256, 0, stream>>>(qkbuf, out + (size_t)2 * 2048 * 2048);
}